// Round 9
// baseline (270.742 us; speedup 1.0000x reference)
//
#include <hip/hip_runtime.h>

// KCenterSampler FPS — round-4 proven sync + truly register-resident coords.
// Round-7 lesson: asm-laundering alone made loads non-rematerializable but the
// RA SPILLED the 72 floats to scratch (VGPR_Count stayed 64; scratch refills
// from L2 cost the same as reloads -> zero time delta). Fix: pin occupancy to
// 1 wave/EU via amdgpu_waves_per_eu(1,1) so the allocator sees the full
// 512-VGPR budget. 128 blocks <= 256 CUs -> 1 block/CU, 4 waves on 4 SIMDs:
// no real occupancy change; cooperative co-residency still guaranteed.
// Sync leg byte-identical to round 4 (agent-scope RELAXED u64 slots).
// Arithmetic bit-identical to the verified round-1/3/4/7 kernels (absmax 0).

#define NPTS 6272
#define CDIM 35
#define BT   8
#define KSEL 128
#define THW  12544
#define BPS  16                  // blocks per segment
#define PPB  392                 // points per block
#define BLK  256
#define NB   (BT * BPS)          // 128 blocks
#define TAILN (PPB - BLK)        // 136: threads owning a 2nd point

__device__ __forceinline__ unsigned long long key_of(float v, int j) {
  unsigned int u = __float_as_uint(v);
  u = (u & 0x80000000u) ? ~u : (u | 0x80000000u);   // monotone float->uint
  return ((unsigned long long)u << 32) | (unsigned int)(NPTS - j); // low!=0
}
__device__ __forceinline__ unsigned long long kmax(unsigned long long a,
                                                   unsigned long long b) {
  return a > b ? a : b;
}

__global__ __attribute__((amdgpu_waves_per_eu(1, 1))) __launch_bounds__(BLK)
void fps_kernel(const float* __restrict__ x,
                const int* __restrict__ init_,
                int* __restrict__ out_idx,
                unsigned long long* __restrict__ slots) {
  __shared__ unsigned long long wk[4];
  __shared__ int far_s;

  const int bid  = (int)blockIdx.x;
  const int b    = bid / BPS;          // segment 0..7
  const int sub  = bid % BPS;          // sub-block within segment
  const int tid  = (int)threadIdx.x;
  const int lane = tid & 63;
  const int wid  = tid >> 6;
  const int j0   = sub * PPB;
  const float* xg = x + (size_t)b * NPTS * CDIM;
  unsigned long long* seg = slots + (size_t)b * KSEL * BPS;

  // ---- one-time load: coords -> VGPRs (laundered), sq sequential ----
  float xr0[CDIM], xr1[CDIM];
  float sqr0, sqr1, df0, df1;
  {
    const float* src0 = xg + (size_t)(j0 + tid) * CDIM;
    float acc = 0.0f;
    {
#pragma clang fp contract(off)
#pragma unroll
      for (int c = 0; c < CDIM; ++c) { float v = src0[c]; xr0[c] = v; acc = acc + v * v; }
    }
    sqr0 = acc; df0 = 50000.0f;
    sqr1 = 0.0f; df1 = 50000.0f;
#pragma unroll
    for (int c = 0; c < CDIM; ++c) xr1[c] = 0.0f;
    if (tid < TAILN) {
      const float* src1 = xg + (size_t)(j0 + BLK + tid) * CDIM;
      float acc1 = 0.0f;
      {
#pragma clang fp contract(off)
#pragma unroll
        for (int c = 0; c < CDIM; ++c) { float v = src1[c]; xr1[c] = v; acc1 = acc1 + v * v; }
      }
      sqr1 = acc1;
    }
    // launder: opaque defs — compiler cannot re-materialize from memory
#pragma unroll
    for (int c = 0; c < CDIM; ++c) {
      asm volatile("" : "+v"(xr0[c]));
      asm volatile("" : "+v"(xr1[c]));
    }
    asm volatile("" : "+v"(sqr0));
    asm volatile("" : "+v"(sqr1));
  }

  int far;
  { int f = init_[b] % NPTS; if (f < 0) f += NPTS; far = f; }  // jnp.remainder
  if (sub == 0 && tid == 0) out_idx[b * KSEL] = far;

  // ---- 127 sequential FPS steps ----
  for (int step = 1; step < KSEL; ++step) {
    // farthest point's coords: uniform-address broadcast loads (L2-hit)
    const int fu = __builtin_amdgcn_readfirstlane(far);
    const float* fx = xg + (size_t)fu * CDIM;
    float xf[CDIM];
#pragma unroll
    for (int c = 0; c < CDIM; ++c) xf[c] = fx[c];

    // sqf: sequential chain from identical f32 values -> bitwise equal;
    // depends only on xf, overlaps the dot chains.
    float sqf;
    {
#pragma clang fp contract(off)
      float a = 0.0f;
#pragma unroll
      for (int c = 0; c < CDIM; ++c) { float t = xf[c]; a = a + t * t; }
      sqf = a;
    }

    // point 0 (all threads)
    unsigned long long bk;
    {
      float dot = 0.0f;
#pragma unroll
      for (int c = 0; c < CDIM; ++c)
        dot = __builtin_fmaf(xf[c], xr0[c], dot);          // k-sequential FMA
      float d2;
      {
#pragma clang fp contract(off)
        d2 = (sqf + sqr0) - 2.0f * dot;                    // reference order
      }
      d2 = fmaxf(d2, 0.0f);
      float d = __fsqrt_rn(d2);
      const int j = j0 + tid;
      d = (j == far) ? -1.0f : d;                          // diagonal = -1
      float nd = fminf(d, df0);                            // f32 min-carry
      df0 = nd;
      bk = key_of(nd, j);
    }
    // point 1 (threads 0..135)
    if (tid < TAILN) {
      float dot = 0.0f;
#pragma unroll
      for (int c = 0; c < CDIM; ++c)
        dot = __builtin_fmaf(xf[c], xr1[c], dot);
      float d2;
      {
#pragma clang fp contract(off)
        d2 = (sqf + sqr1) - 2.0f * dot;
      }
      d2 = fmaxf(d2, 0.0f);
      float d = __fsqrt_rn(d2);
      const int j = j0 + BLK + tid;
      d = (j == far) ? -1.0f : d;
      float nd = fminf(d, df1);
      df1 = nd;
      bk = kmax(bk, key_of(nd, j));
    }

    // wave-level max of packed keys (order = (value, first-index))
#pragma unroll
    for (int off = 32; off > 0; off >>= 1)
      bk = kmax(bk, __shfl_down(bk, off));
    if (lane == 0) wk[wid] = bk;
    __syncthreads();                                       // barrier 1

    if (tid < BPS) {
      if (tid == 0) {
        unsigned long long m = kmax(kmax(wk[0], wk[1]), kmax(wk[2], wk[3]));
        // payload self-contained -> RELAXED agent scope, no fence
        __hip_atomic_store(&seg[step * BPS + sub], m,
                           __ATOMIC_RELAXED, __HIP_MEMORY_SCOPE_AGENT);
      }
      asm volatile("" ::: "memory");   // keep store ahead of the spin loop
      unsigned long long k;
      do {
        k = __hip_atomic_load(&seg[step * BPS + tid],
                              __ATOMIC_RELAXED, __HIP_MEMORY_SCOPE_AGENT);
      } while (k == 0ull);
      // in-wave max over the 16 polled keys (lanes 0..15)
#pragma unroll
      for (int off = 8; off > 0; off >>= 1)
        k = kmax(k, __shfl_down(k, off));
      if (tid == 0) {
        int f = NPTS - (int)(unsigned int)(k & 0xFFFFFFFFull);
        far_s = f;
        if (sub == 0) out_idx[b * KSEL + step] = f;
      }
    }
    __syncthreads();                                       // barrier 2
    far = far_s;
  }
}

// ---------------------------------------------------------------------------
// gather patches (first 32 channels) + write indices (as f32)
// ---------------------------------------------------------------------------
__global__ __launch_bounds__(256) void gather_kernel(const float* __restrict__ x,
                                                     const int* __restrict__ out_idx,
                                                     float* __restrict__ patches,
                                                     float* __restrict__ sidx) {
  const int b = (int)blockIdx.x;     // 0..3
  const int m = (int)threadIdx.x;    // 0..255
  const int td = m >> 7;             // time segment 0/1
  const int i  = m & 127;
  const int li = out_idx[(b * 2 + td) * KSEL + i];
  const int gi = li + td * NPTS;
  sidx[b * 256 + m] = (float)gi;
  const float* src = x + ((size_t)b * THW + gi) * CDIM;
  float* dst = patches + ((size_t)b * 256 + m) * 32;
#pragma unroll
  for (int c = 0; c < 32; ++c) dst[c] = src[c];   // first C-3 channels
}

extern "C" void kernel_launch(void* const* d_in, const int* in_sizes, int n_in,
                              void* d_out, int out_size, void* d_ws, size_t ws_size,
                              hipStream_t stream) {
  const float* x    = (const float*)d_in[0];
  const int*   init = (const int*)d_in[1];
  (void)in_sizes; (void)n_in; (void)out_size; (void)ws_size;

  // ws layout: slots [BT*KSEL*BPS u64] | idx [BT*KSEL int]
  unsigned long long* slots = (unsigned long long*)d_ws;
  const size_t slots_bytes = (size_t)BT * KSEL * BPS * sizeof(unsigned long long);
  int* idx = (int*)((char*)d_ws + slots_bytes);

  float* patches = (float*)d_out;
  float* sidx    = patches + (size_t)4 * 256 * 32;

  hipMemsetAsync(d_ws, 0, slots_bytes, stream);   // zero sync slots per launch

  void* kargs[] = { (void*)&x, (void*)&init, (void*)&idx, (void*)&slots };
  hipLaunchCooperativeKernel((const void*)fps_kernel, dim3(NB), dim3(BLK),
                             kargs, 0, stream);

  hipLaunchKernelGGL(gather_kernel, dim3(4), dim3(256), 0, stream,
                     x, idx, patches, sidx);
}

// Round 10
// 243.660 us; speedup vs baseline: 1.1111x; 1.1111x over previous
//
#include <hip/hip_runtime.h>

// KCenterSampler FPS — round-4 proven sync structure + dual-path (same-XCD
// L2 fast / agent-scope LLC slow) winner exchange.
//
// 8 segments × 16 blocks (128 blocks, cooperative). segment = bid&7 so
// round-robin dispatch co-locates a segment's 16 blocks on one XCD.
// Publisher stores the packed winner key to BOTH a fast slot (sc0 store:
// write-through to the local XCD L2) and the proven agent-scope slow slot
// (LLC). Pollers issue both loads in ONE asm block (early-clobbered outputs
// — round-6's hang was a missing "&": the load clobbered its own address
// pair) and accept whichever slot is nonzero first. Slots are written once
// (0 -> key, 8B aligned single instruction), so any mix of paths is correct;
// the slow path alone guarantees progress (no deadlock by construction).
//
// Coords/sq/dist in VGPRs (waves_per_eu(1,1), asm-laundered; VGPR=132,
// verified round 8). Arithmetic bit-identical to rounds 1/3/4/8 (absmax 0).

#define NPTS 6272
#define CDIM 35
#define BT   8
#define KSEL 128
#define THW  12544
#define BPS  16                  // blocks per segment
#define PPB  392                 // points per block
#define BLK  256
#define NB   (BT * BPS)          // 128 blocks
#define TAILN (PPB - BLK)        // 136: threads owning a 2nd point

__device__ __forceinline__ unsigned long long key_of(float v, int j) {
  unsigned int u = __float_as_uint(v);
  u = (u & 0x80000000u) ? ~u : (u | 0x80000000u);   // monotone float->uint
  return ((unsigned long long)u << 32) | (unsigned int)(NPTS - j); // low!=0
}
__device__ __forceinline__ unsigned long long kmax(unsigned long long a,
                                                   unsigned long long b) {
  return a > b ? a : b;
}

// publish to both paths: fast = sc0 (local-XCD L2 write-through),
// slow = agent scope (LLC, proven visible cross-XCD).
__device__ __forceinline__ void dual_store(unsigned long long* fp,
                                           unsigned long long* sp,
                                           unsigned long long v) {
  asm volatile("global_store_dwordx2 %0, %1, off sc0"
               :: "v"(fp), "v"(v) : "memory");
  __hip_atomic_store(sp, v, __ATOMIC_RELAXED, __HIP_MEMORY_SCOPE_AGENT);
}

// one retry = both loads in flight, single vmcnt wait. "=&v" early-clobber
// is REQUIRED: without it the result may alias the address pair (round-6 hang).
__device__ __forceinline__ void dual_load(const unsigned long long* fp,
                                          const unsigned long long* sp,
                                          unsigned long long& kf,
                                          unsigned long long& ks) {
  asm volatile("global_load_dwordx2 %0, %2, off sc0\n\t"
               "global_load_dwordx2 %1, %3, off sc0 sc1\n\t"
               "s_waitcnt vmcnt(0)"
               : "=&v"(kf), "=&v"(ks)
               : "v"(fp), "v"(sp)
               : "memory");
}

__global__ __attribute__((amdgpu_waves_per_eu(1, 1))) __launch_bounds__(BLK)
void fps_kernel(const float* __restrict__ x,
                const int* __restrict__ init_,
                int* __restrict__ out_idx,
                unsigned long long* __restrict__ slow_slots,
                unsigned long long* __restrict__ fast_slots) {
  __shared__ unsigned long long wk[4];
  __shared__ int far_s;

  const int bid  = (int)blockIdx.x;
  const int b    = bid & 7;            // segment: round-robin -> same XCD
  const int sub  = bid >> 3;           // sub-block 0..15 within segment
  const int tid  = (int)threadIdx.x;
  const int lane = tid & 63;
  const int wid  = tid >> 6;
  const int j0   = sub * PPB;
  const float* xg = x + (size_t)b * NPTS * CDIM;
  unsigned long long* sseg = slow_slots + (size_t)b * KSEL * BPS;
  unsigned long long* fseg = fast_slots + (size_t)b * KSEL * BPS;

  // ---- one-time load: coords -> VGPRs (laundered), sq sequential ----
  float xr0[CDIM], xr1[CDIM];
  float sqr0, sqr1, df0, df1;
  {
    const float* src0 = xg + (size_t)(j0 + tid) * CDIM;
    float acc = 0.0f;
    {
#pragma clang fp contract(off)
#pragma unroll
      for (int c = 0; c < CDIM; ++c) { float v = src0[c]; xr0[c] = v; acc = acc + v * v; }
    }
    sqr0 = acc; df0 = 50000.0f;
    sqr1 = 0.0f; df1 = 50000.0f;
#pragma unroll
    for (int c = 0; c < CDIM; ++c) xr1[c] = 0.0f;
    if (tid < TAILN) {
      const float* src1 = xg + (size_t)(j0 + BLK + tid) * CDIM;
      float acc1 = 0.0f;
      {
#pragma clang fp contract(off)
#pragma unroll
        for (int c = 0; c < CDIM; ++c) { float v = src1[c]; xr1[c] = v; acc1 = acc1 + v * v; }
      }
      sqr1 = acc1;
    }
#pragma unroll
    for (int c = 0; c < CDIM; ++c) {
      asm volatile("" : "+v"(xr0[c]));
      asm volatile("" : "+v"(xr1[c]));
    }
    asm volatile("" : "+v"(sqr0));
    asm volatile("" : "+v"(sqr1));
  }

  int far;
  { int f = init_[b] % NPTS; if (f < 0) f += NPTS; far = f; }  // jnp.remainder
  if (sub == 0 && tid == 0) out_idx[b * KSEL] = far;

  // ---- 127 sequential FPS steps ----
  for (int step = 1; step < KSEL; ++step) {
    // farthest point's coords: uniform-address broadcast loads (L2-hit)
    const int fu = __builtin_amdgcn_readfirstlane(far);
    const float* fx = xg + (size_t)fu * CDIM;
    float xf[CDIM];
#pragma unroll
    for (int c = 0; c < CDIM; ++c) xf[c] = fx[c];

    // sqf: sequential chain from identical f32 values -> bitwise equal
    float sqf;
    {
#pragma clang fp contract(off)
      float a = 0.0f;
#pragma unroll
      for (int c = 0; c < CDIM; ++c) { float t = xf[c]; a = a + t * t; }
      sqf = a;
    }

    // point 0 (all threads)
    unsigned long long bk;
    {
      float dot = 0.0f;
#pragma unroll
      for (int c = 0; c < CDIM; ++c)
        dot = __builtin_fmaf(xf[c], xr0[c], dot);          // k-sequential FMA
      float d2;
      {
#pragma clang fp contract(off)
        d2 = (sqf + sqr0) - 2.0f * dot;                    // reference order
      }
      d2 = fmaxf(d2, 0.0f);
      float d = __fsqrt_rn(d2);
      const int j = j0 + tid;
      d = (j == far) ? -1.0f : d;                          // diagonal = -1
      float nd = fminf(d, df0);                            // f32 min-carry
      df0 = nd;
      bk = key_of(nd, j);
    }
    // point 1 (threads 0..135)
    if (tid < TAILN) {
      float dot = 0.0f;
#pragma unroll
      for (int c = 0; c < CDIM; ++c)
        dot = __builtin_fmaf(xf[c], xr1[c], dot);
      float d2;
      {
#pragma clang fp contract(off)
        d2 = (sqf + sqr1) - 2.0f * dot;
      }
      d2 = fmaxf(d2, 0.0f);
      float d = __fsqrt_rn(d2);
      const int j = j0 + BLK + tid;
      d = (j == far) ? -1.0f : d;
      float nd = fminf(d, df1);
      df1 = nd;
      bk = kmax(bk, key_of(nd, j));
    }

    // wave-level max of packed keys (order = (value, first-index))
#pragma unroll
    for (int off = 32; off > 0; off >>= 1)
      bk = kmax(bk, __shfl_down(bk, off));
    if (lane == 0) wk[wid] = bk;
    __syncthreads();                                       // barrier 1

    if (tid < BPS) {
      if (tid == 0) {
        unsigned long long m = kmax(kmax(wk[0], wk[1]), kmax(wk[2], wk[3]));
        dual_store(&fseg[step * BPS + sub], &sseg[step * BPS + sub], m);
      }
      asm volatile("" ::: "memory");   // keep stores ahead of the spin loop
      // dual poll: accept fast (same-XCD L2) or slow (LLC), whichever first
      unsigned long long k = 0ull;
      const unsigned long long* fp = &fseg[step * BPS + tid];
      const unsigned long long* sp = &sseg[step * BPS + tid];
      do {
        unsigned long long kf, ks;
        dual_load(fp, sp, kf, ks);
        k = ks ? ks : kf;
      } while (k == 0ull);
      // in-wave max over the 16 polled keys (lanes 0..15)
#pragma unroll
      for (int off = 8; off > 0; off >>= 1)
        k = kmax(k, __shfl_down(k, off));
      if (tid == 0) {
        int f = NPTS - (int)(unsigned int)(k & 0xFFFFFFFFull);
        far_s = f;
        if (sub == 0) out_idx[b * KSEL + step] = f;
      }
    }
    __syncthreads();                                       // barrier 2
    far = far_s;
  }
}

// ---------------------------------------------------------------------------
// gather patches (first 32 channels) + write indices (as f32)
// ---------------------------------------------------------------------------
__global__ __launch_bounds__(256) void gather_kernel(const float* __restrict__ x,
                                                     const int* __restrict__ out_idx,
                                                     float* __restrict__ patches,
                                                     float* __restrict__ sidx) {
  const int b = (int)blockIdx.x;     // 0..3
  const int m = (int)threadIdx.x;    // 0..255
  const int td = m >> 7;             // time segment 0/1
  const int i  = m & 127;
  const int li = out_idx[(b * 2 + td) * KSEL + i];
  const int gi = li + td * NPTS;
  sidx[b * 256 + m] = (float)gi;
  const float* src = x + ((size_t)b * THW + gi) * CDIM;
  float* dst = patches + ((size_t)b * 256 + m) * 32;
#pragma unroll
  for (int c = 0; c < 32; ++c) dst[c] = src[c];   // first C-3 channels
}

extern "C" void kernel_launch(void* const* d_in, const int* in_sizes, int n_in,
                              void* d_out, int out_size, void* d_ws, size_t ws_size,
                              hipStream_t stream) {
  const float* x    = (const float*)d_in[0];
  const int*   init = (const int*)d_in[1];
  (void)in_sizes; (void)n_in; (void)out_size; (void)ws_size;

  // ws layout: slow [BT*KSEL*BPS u64] | fast [BT*KSEL*BPS u64] | idx [ints]
  const size_t arr = (size_t)BT * KSEL * BPS * sizeof(unsigned long long);
  unsigned long long* slow_slots = (unsigned long long*)d_ws;
  unsigned long long* fast_slots = (unsigned long long*)((char*)d_ws + arr);
  int* idx = (int*)((char*)d_ws + 2 * arr);

  float* patches = (float*)d_out;
  float* sidx    = patches + (size_t)4 * 256 * 32;

  hipMemsetAsync(d_ws, 0, 2 * arr, stream);   // zero both slot arrays

  void* kargs[] = { (void*)&x, (void*)&init, (void*)&idx,
                    (void*)&slow_slots, (void*)&fast_slots };
  hipLaunchCooperativeKernel((const void*)fps_kernel, dim3(NB), dim3(BLK),
                             kargs, 0, stream);

  hipLaunchKernelGGL(gather_kernel, dim3(4), dim3(256), 0, stream,
                     x, idx, patches, sidx);
}